// Round 4
// baseline (322.373 us; speedup 1.0000x reference)
//
#include <hip/hip_runtime.h>

#define N_TRACES 128
#define TLEN 32
#define IN_DIM 64
#define HID 128
#define G4 (4 * HID)            // 512 gate rows
#define BATCH (N_TRACES * TLEN) // 4096
#define TPB 16                  // traces per block
#define NBLK (N_TRACES / TPB)   // 8 blocks
#define HPAD 136                // LDS h row: 272B stride, 68 words, 68%32=4 -> <=2-way conflicts

typedef float f32x4 __attribute__((ext_vector_type(4)));
typedef __bf16 bf16x8 __attribute__((ext_vector_type(8)));

// ---------- device helpers ----------

__device__ __forceinline__ float fast_sigmoid(float x) {
    return 1.0f / (1.0f + __expf(-x));
}
// tanh(x) = 1 - 2/(e^{2x}+1): stable at both extremes
__device__ __forceinline__ float fast_tanh(float x) {
    return 1.0f - 2.0f / (__expf(2.0f * x) + 1.0f);
}

// ---------- input GEMM: out[M][512] = A[M][64] * W[512][64]^T + b1 + b2 ----------
// (unchanged, verified)

template <int K>
__global__ __launch_bounds__(256) void gemm_bt(
    const float* __restrict__ A,
    const float* __restrict__ W,
    const float* __restrict__ b1,
    const float* __restrict__ b2,
    float* __restrict__ out,
    int Nld)
{
    constexpr int LD = 68;
    __shared__ float At[K][LD];
    __shared__ float Wt[K][LD];

    const int tid = threadIdx.x;
    const int m0 = blockIdx.x * 64;
    const int n0 = blockIdx.y * 64;

    const int rot = tid & 3;
    #pragma unroll
    for (int j = 0; j < K / 16; ++j) {
        const int e = 4 * (tid + 256 * j);
        const int row = e / K;
        const int k = e % K;
        float4 va = *(const float4*)(A + (size_t)(m0 + row) * K + k);
        float4 vw = *(const float4*)(W + (size_t)(n0 + row) * K + k);
        float fa[4] = {va.x, va.y, va.z, va.w};
        float fw[4] = {vw.x, vw.y, vw.z, vw.w};
        #pragma unroll
        for (int ii = 0; ii < 4; ++ii) {
            const int i = (ii + rot) & 3;
            At[k + i][row] = fa[i];
            Wt[k + i][row] = fw[i];
        }
    }
    __syncthreads();

    const int tx = tid & 15;
    const int ty = tid >> 4;
    float acc[4][4] = {};

    #pragma unroll 4
    for (int k = 0; k < K; ++k) {
        float4 a = *(const float4*)&At[k][ty * 4];
        float4 w = *(const float4*)&Wt[k][tx * 4];
        acc[0][0] = fmaf(a.x, w.x, acc[0][0]); acc[0][1] = fmaf(a.x, w.y, acc[0][1]);
        acc[0][2] = fmaf(a.x, w.z, acc[0][2]); acc[0][3] = fmaf(a.x, w.w, acc[0][3]);
        acc[1][0] = fmaf(a.y, w.x, acc[1][0]); acc[1][1] = fmaf(a.y, w.y, acc[1][1]);
        acc[1][2] = fmaf(a.y, w.z, acc[1][2]); acc[1][3] = fmaf(a.y, w.w, acc[1][3]);
        acc[2][0] = fmaf(a.z, w.x, acc[2][0]); acc[2][1] = fmaf(a.z, w.y, acc[2][1]);
        acc[2][2] = fmaf(a.z, w.z, acc[2][2]); acc[2][3] = fmaf(a.z, w.w, acc[2][3]);
        acc[3][0] = fmaf(a.w, w.x, acc[3][0]); acc[3][1] = fmaf(a.w, w.y, acc[3][1]);
        acc[3][2] = fmaf(a.w, w.z, acc[3][2]); acc[3][3] = fmaf(a.w, w.w, acc[3][3]);
    }

    float bb[4];
    #pragma unroll
    for (int j = 0; j < 4; ++j) {
        const int n = n0 + tx * 4 + j;
        bb[j] = b1[n] + b2[n];
    }
    #pragma unroll
    for (int i = 0; i < 4; ++i) {
        const int m = m0 + ty * 4 + i;
        float4 v;
        v.x = acc[i][0] + bb[0]; v.y = acc[i][1] + bb[1];
        v.z = acc[i][2] + bb[2]; v.w = acc[i][3] + bb[3];
        *(float4*)(out + (size_t)m * Nld + n0 + tx * 4) = v;
    }
}

// ---------- MFMA fused kernel helpers ----------

// Per-wave B-operand fragments: 64 gate rows {u + 128*gi} of a [512][128] f32
// matrix, hi/lo bf16 split. Lane supplies row u = 16w + (lane&15), k-chunk
// 8*(lane>>4) within each 32-wide kc window (m92-verified frag convention).
__device__ __forceinline__ void load_wfrag(const float* __restrict__ W, int u, int q,
                                           bf16x8 (&bh)[4][4], bf16x8 (&bl)[4][4])
{
    #pragma unroll
    for (int gi = 0; gi < 4; ++gi) {
        const float* wr = W + (size_t)(u + 128 * gi) * HID + 8 * q;
        #pragma unroll
        for (int kc = 0; kc < 4; ++kc) {
            float4 v0 = *(const float4*)(wr + 32 * kc);
            float4 v1 = *(const float4*)(wr + 32 * kc + 4);
            float f0[4] = {v0.x, v0.y, v0.z, v0.w};
            float f1[4] = {v1.x, v1.y, v1.z, v1.w};
            bf16x8 h, l;
            #pragma unroll
            for (int e = 0; e < 4; ++e) {
                __bf16 t0 = (__bf16)f0[e];
                h[e] = t0; l[e] = (__bf16)(f0[e] - (float)t0);
                __bf16 t1 = (__bf16)f1[e];
                h[4 + e] = t1; l[4 + e] = (__bf16)(f1[e] - (float)t1);
            }
            bh[gi][kc] = h; bl[gi][kc] = l;
        }
    }
}

// One recurrent matvec step for this wave: acc[gi] += W[64 gate rows] @ h.
// A-frags (h hi/lo) from LDS staging; 3-term hi/lo product (Wlo*hlo dropped).
__device__ __forceinline__ void matstep(
    const __bf16 (&shi)[TPB][HPAD], const __bf16 (&slo)[TPB][HPAD],
    const bf16x8 (&bh)[4][4], const bf16x8 (&bl)[4][4],
    int cl, int q, f32x4 (&acc)[4])
{
    bf16x8 ah[4], al[4];
    #pragma unroll
    for (int kc = 0; kc < 4; ++kc) {
        ah[kc] = *(const bf16x8*)&shi[cl][32 * kc + 8 * q];
        al[kc] = *(const bf16x8*)&slo[cl][32 * kc + 8 * q];
    }
    #pragma unroll
    for (int gi = 0; gi < 4; ++gi) {
        #pragma unroll
        for (int kc = 0; kc < 4; ++kc) {
            acc[gi] = __builtin_amdgcn_mfma_f32_16x16x32_bf16(ah[kc], bh[gi][kc], acc[gi], 0, 0, 0);
            acc[gi] = __builtin_amdgcn_mfma_f32_16x16x32_bf16(al[kc], bh[gi][kc], acc[gi], 0, 0, 0);
            acc[gi] = __builtin_amdgcn_mfma_f32_16x16x32_bf16(ah[kc], bl[gi][kc], acc[gi], 0, 0, 0);
        }
    }
}

// Gate nonlinearity + c/h update for this lane's 4 (trace, unit) pairs,
// then stage h (hi/lo bf16) into LDS and dump to global scratch.
// acc[gi][r]: gate gi preactivation (recurrent part) for trace m=4q+r.
__device__ __forceinline__ void gate_stage(
    const f32x4 (&acc)[4], const f32x4 (&xg)[4], const float (&bias)[4],
    float (&cst)[4], int q, int u,
    __bf16 (&shi)[TPB][HPAD], __bf16 (&slo)[TPB][HPAD],
    __bf16* __restrict__ dhi, __bf16* __restrict__ dlo)
{
    #pragma unroll
    for (int r = 0; r < 4; ++r) {
        const int m = 4 * q + r;
        const float gI = acc[0][r] + xg[0][r] + bias[0];
        const float gF = acc[1][r] + xg[1][r] + bias[1];
        const float gG = acc[2][r] + xg[2][r] + bias[2];
        const float gO = acc[3][r] + xg[3][r] + bias[3];
        const float iv = fast_sigmoid(gI);
        const float fv = fast_sigmoid(gF);
        const float gv = fast_tanh(gG);
        const float ov = fast_sigmoid(gO);
        cst[r] = fv * cst[r] + iv * gv;
        const float h = ov * fast_tanh(cst[r]);
        const __bf16 hb = (__bf16)h;
        const __bf16 lb = (__bf16)(h - (float)hb);
        shi[m][u] = hb;
        slo[m][u] = lb;
        dhi[(size_t)m * HID + u] = hb;
        dlo[(size_t)m * HID + u] = lb;
    }
}

// ---------- fused per-16-trace MFMA kernel (8 blocks x 512 threads) ----------
// r9 redesign: recurrence matvec on the matrix pipe. Wave w owns units
// [16w,16w+16) -> gate rows {u, u+128, u+256, u+384} (4 N-tiles of 16).
// M = 16 traces, K = 128 (4 chunks), mfma_f32_16x16x32_bf16, hi/lo split
// 3-term for ~fp32 precision. All 4 gates + c + h of a (trace,unit) pair land
// in one lane (D col=lane&15 picks the unit, rows = traces). h round-trips
// through a double-buffered LDS tile (16B-aligned, <=2-way banked) to become
// the next step's A-fragments. xg streams from xproj0 with 1-step register
// prefetch; layer-1 input projection is a separate no-barrier MFMA pass via
// block-private global scratch (intra-CU RAW, ordered by __syncthreads).

__global__ __launch_bounds__(512, 2) void fused_mfma(
    const float* __restrict__ xproj0, // [4096][512] (incl. both layer-0 biases)
    const float* __restrict__ Whh0,   // [512][128]
    const float* __restrict__ Wih1,   // [512][128]
    const float* __restrict__ bih1,   // [512]
    const float* __restrict__ bhh1,   // [512]
    const float* __restrict__ Whh1,   // [512][128]
    const float* __restrict__ Wlin,   // [128]
    const float* __restrict__ blin,   // [1]
    float* __restrict__ xp1d,         // [NBLK][TLEN][8][4][64][4] f32 scratch
    __bf16* __restrict__ h1hi,        // [NBLK][TLEN][TPB][HID]
    __bf16* __restrict__ h1lo,
    __bf16* __restrict__ h2hi,
    __bf16* __restrict__ h2lo,
    float* __restrict__ y)            // [4096]
{
    const int b = blockIdx.x;
    const int tid = threadIdx.x;
    const int w = tid >> 6;        // wave 0..7
    const int lane = tid & 63;
    const int cl = lane & 15;      // operand-row selector (trace for A, gate for B)
    const int q = lane >> 4;       // k-chunk selector; D-row group (traces 4q..4q+3)
    const int u = 16 * w + cl;     // this lane's hidden unit (gate cols u+128*gi)

    __shared__ __align__(16) __bf16 Shi[2][TPB][HPAD];
    __shared__ __align__(16) __bf16 Slo[2][TPB][HPAD];

    const size_t hob = (size_t)b * TLEN * TPB * HID; // 65536
    __bf16* h1hi_b = h1hi + hob;
    __bf16* h1lo_b = h1lo + hob;
    __bf16* h2hi_b = h2hi + hob;
    __bf16* h2lo_b = h2lo + hob;
    float* xp1_b = xp1d + (size_t)b * TLEN * 8192;

    bf16x8 bh[4][4], bl[4][4];
    const float zb[4] = {0.f, 0.f, 0.f, 0.f};

    // xg row base pointers, one per r (global trace = 16b + 4q + r)
    const float* xb[4];
    #pragma unroll
    for (int r = 0; r < 4; ++r)
        xb[r] = xproj0 + (size_t)(16 * b + 4 * q + r) * TLEN * G4 + u;

    // ===== Layer 0 =====
    load_wfrag(Whh0, u, q, bh, bl);

    f32x4 xgc[4], xgn[4];
    #pragma unroll
    for (int gi = 0; gi < 4; ++gi)
        #pragma unroll
        for (int r = 0; r < 4; ++r)
            xgc[gi][r] = xb[r][128 * gi]; // t = 0

    float cst[4] = {0.f, 0.f, 0.f, 0.f};
    {   // t = 0 peel: h(-1)=0 -> gates from xg only
        f32x4 accz[4] = {};
        gate_stage(accz, xgc, zb, cst, q, u, Shi[0], Slo[0], h1hi_b, h1lo_b);
    }
    #pragma unroll
    for (int gi = 0; gi < 4; ++gi)
        #pragma unroll
        for (int r = 0; r < 4; ++r)
            xgn[gi][r] = xb[r][(size_t)1 * G4 + 128 * gi]; // t = 1
    __syncthreads();

    #pragma unroll 1
    for (int t = 1; t < TLEN; ++t) {
        #pragma unroll
        for (int gi = 0; gi < 4; ++gi) xgc[gi] = xgn[gi];
        if (t < TLEN - 1) {
            #pragma unroll
            for (int gi = 0; gi < 4; ++gi)
                #pragma unroll
                for (int r = 0; r < 4; ++r)
                    xgn[gi][r] = xb[r][(size_t)(t + 1) * G4 + 128 * gi];
        }
        f32x4 acc[4] = {};
        matstep(Shi[(t - 1) & 1], Slo[(t - 1) & 1], bh, bl, cl, q, acc);
        gate_stage(acc, xgc, zb, cst, q, u, Shi[t & 1], Slo[t & 1],
                   h1hi_b + (size_t)t * TPB * HID, h1lo_b + (size_t)t * TPB * HID);
        __syncthreads();
    }

    // ===== Phase C: xp1(t) = W_ih1 @ h1(t) for all t (no barriers; waves
    // independent; reads h1 dumps drained by the loop's final barrier) =====
    load_wfrag(Wih1, u, q, bh, bl);
    #pragma unroll 1
    for (int t = 0; t < TLEN; ++t) {
        const __bf16* ph = h1hi_b + ((size_t)t * TPB + cl) * HID + 8 * q;
        const __bf16* pl = h1lo_b + ((size_t)t * TPB + cl) * HID + 8 * q;
        bf16x8 ah[4], al[4];
        #pragma unroll
        for (int kc = 0; kc < 4; ++kc) {
            ah[kc] = *(const bf16x8*)(ph + 32 * kc);
            al[kc] = *(const bf16x8*)(pl + 32 * kc);
        }
        f32x4 acc[4] = {};
        #pragma unroll
        for (int gi = 0; gi < 4; ++gi) {
            #pragma unroll
            for (int kc = 0; kc < 4; ++kc) {
                acc[gi] = __builtin_amdgcn_mfma_f32_16x16x32_bf16(ah[kc], bh[gi][kc], acc[gi], 0, 0, 0);
                acc[gi] = __builtin_amdgcn_mfma_f32_16x16x32_bf16(al[kc], bh[gi][kc], acc[gi], 0, 0, 0);
                acc[gi] = __builtin_amdgcn_mfma_f32_16x16x32_bf16(ah[kc], bl[gi][kc], acc[gi], 0, 0, 0);
            }
        }
        float* po = xp1_b + ((size_t)t * 8 + w) * 1024 + lane * 4;
        #pragma unroll
        for (int gi = 0; gi < 4; ++gi)
            *(f32x4*)(po + gi * 256) = acc[gi];
    }
    __syncthreads(); // drain xp1 stores before layer-1 reads them back

    // ===== Layer 1 =====
    load_wfrag(Whh1, u, q, bh, bl);
    float bias[4];
    #pragma unroll
    for (int gi = 0; gi < 4; ++gi)
        bias[gi] = bih1[u + 128 * gi] + bhh1[u + 128 * gi];

    const float* po_base = xp1_b + w * 1024 + lane * 4;
    f32x4 xpc[4], xpn[4];
    #pragma unroll
    for (int gi = 0; gi < 4; ++gi)
        xpc[gi] = *(const f32x4*)(po_base + gi * 256); // t = 0

    cst[0] = cst[1] = cst[2] = cst[3] = 0.f;
    {   // t = 0 peel
        f32x4 accz[4] = {};
        gate_stage(accz, xpc, bias, cst, q, u, Shi[0], Slo[0], h2hi_b, h2lo_b);
    }
    #pragma unroll
    for (int gi = 0; gi < 4; ++gi)
        xpn[gi] = *(const f32x4*)(po_base + (size_t)1 * 8192 + gi * 256); // t = 1
    __syncthreads();

    #pragma unroll 1
    for (int t = 1; t < TLEN; ++t) {
        #pragma unroll
        for (int gi = 0; gi < 4; ++gi) xpc[gi] = xpn[gi];
        if (t < TLEN - 1) {
            #pragma unroll
            for (int gi = 0; gi < 4; ++gi)
                xpn[gi] = *(const f32x4*)(po_base + (size_t)(t + 1) * 8192 + gi * 256);
        }
        f32x4 acc[4] = {};
        matstep(Shi[(t - 1) & 1], Slo[(t - 1) & 1], bh, bl, cl, q, acc);
        gate_stage(acc, xpc, bias, cst, q, u, Shi[t & 1], Slo[t & 1],
                   h2hi_b + (size_t)t * TPB * HID, h2lo_b + (size_t)t * TPB * HID);
        __syncthreads();
    }

    // ===== Phase E: y = W_lin . h2(t) + b_lin ; one (t, trace) pair/thread =====
    {
        const int t = tid >> 4;
        const int tr = tid & 15;
        const __bf16* ph = h2hi_b + ((size_t)t * TPB + tr) * HID;
        const __bf16* pl = h2lo_b + ((size_t)t * TPB + tr) * HID;
        float a = 0.f;
        #pragma unroll
        for (int j = 0; j < 16; ++j) {
            bf16x8 vh = *(const bf16x8*)(ph + 8 * j);
            bf16x8 vl = *(const bf16x8*)(pl + 8 * j);
            float4 w0 = *(const float4*)(Wlin + 8 * j);
            float4 w1 = *(const float4*)(Wlin + 8 * j + 4);
            a = fmaf((float)vh[0] + (float)vl[0], w0.x, a);
            a = fmaf((float)vh[1] + (float)vl[1], w0.y, a);
            a = fmaf((float)vh[2] + (float)vl[2], w0.z, a);
            a = fmaf((float)vh[3] + (float)vl[3], w0.w, a);
            a = fmaf((float)vh[4] + (float)vl[4], w1.x, a);
            a = fmaf((float)vh[5] + (float)vl[5], w1.y, a);
            a = fmaf((float)vh[6] + (float)vl[6], w1.z, a);
            a = fmaf((float)vh[7] + (float)vl[7], w1.w, a);
        }
        y[(size_t)(16 * b + tr) * TLEN + t] = a + blin[0];
    }
}

// ---------- launch ----------

extern "C" void kernel_launch(void* const* d_in, const int* in_sizes, int n_in,
                              void* d_out, int out_size, void* d_ws, size_t ws_size,
                              hipStream_t stream) {
    const float* input = (const float*)d_in[0];  // [4096][64]
    const float* W_ih0 = (const float*)d_in[1];  // [512][64]
    const float* W_hh0 = (const float*)d_in[2];  // [512][128]
    const float* b_ih0 = (const float*)d_in[3];  // [512]
    const float* b_hh0 = (const float*)d_in[4];  // [512]
    const float* W_ih1 = (const float*)d_in[5];  // [512][128]
    const float* W_hh1 = (const float*)d_in[6];  // [512][128]
    const float* b_ih1 = (const float*)d_in[7];  // [512]
    const float* b_hh1 = (const float*)d_in[8];  // [512]
    const float* W_lin = (const float*)d_in[9];  // [1][128]
    const float* b_lin = (const float*)d_in[10]; // [1]
    float* out = (float*)d_out;                  // [4096]

    // workspace map (20 MB, disjoint regions)
    float*  xproj0 = (float*)d_ws;                             // 8 MB
    float*  xp1d   = (float*)((char*)d_ws + (size_t)(8 << 20));  // 8 MB
    __bf16* h1hi   = (__bf16*)((char*)d_ws + (size_t)(16 << 20)); // 1 MB
    __bf16* h1lo   = (__bf16*)((char*)d_ws + (size_t)(17 << 20)); // 1 MB
    __bf16* h2hi   = (__bf16*)((char*)d_ws + (size_t)(18 << 20)); // 1 MB
    __bf16* h2lo   = (__bf16*)((char*)d_ws + (size_t)(19 << 20)); // 1 MB

    dim3 ggrid(BATCH / 64, G4 / 64); // (64, 8)

    // K1: xproj0 = input @ W_ih0^T + b_ih0 + b_hh0 (full-chip GEMM)
    gemm_bt<IN_DIM><<<ggrid, 256, 0, stream>>>(input, W_ih0, b_ih0, b_hh0, xproj0, G4);
    // K2: batched-trace MFMA LSTM0 -> xp1 -> LSTM1 -> linear readout
    fused_mfma<<<NBLK, 512, 0, stream>>>(xproj0, W_hh0, W_ih1, b_ih1, b_hh1,
                                         W_hh1, W_lin, b_lin,
                                         xp1d, h1hi, h1lo, h2hi, h2lo, out);
}

// Round 5
// 229.624 us; speedup vs baseline: 1.4039x; 1.4039x over previous
//
#include <hip/hip_runtime.h>

#define N_TRACES 128
#define TLEN 32
#define IN_DIM 64
#define HID 128
#define G4 (4 * HID)            // 512 gate rows
#define BATCH (N_TRACES * TLEN) // 4096

// ---------- device helpers ----------

__device__ __forceinline__ float fast_sigmoid(float x) {
    return 1.0f / (1.0f + __expf(-x));
}
// tanh(x) = 1 - 2/(e^{2x}+1): stable at both extremes
__device__ __forceinline__ float fast_tanh(float x) {
    return 1.0f - 2.0f / (__expf(2.0f * x) + 1.0f);
}
// sum across the 4 lanes of a quad, result in all 4 lanes
__device__ __forceinline__ float quad_reduce(float x) {
    x += __int_as_float(__builtin_amdgcn_update_dpp(
        0, __float_as_int(x), 0xB1 /*quad_perm [1,0,3,2]*/, 0xF, 0xF, true));
    x += __int_as_float(__builtin_amdgcn_update_dpp(
        0, __float_as_int(x), 0x4E /*quad_perm [2,3,0,1]*/, 0xF, 0xF, true));
    return x;
}
// full LSTM gate update for one (trace, unit): returns h, updates c
__device__ __forceinline__ float lstm_gate(const float (&acc)[4], const float (&xg)[4],
                                           float& c) {
    const float iv = fast_sigmoid(acc[0] + xg[0]);
    const float fv = fast_sigmoid(acc[1] + xg[1]);
    const float gv = fast_tanh(acc[2] + xg[2]);
    const float ov = fast_sigmoid(acc[3] + xg[3]);
    c = fv * c + iv * gv;
    return ov * fast_tanh(c);
}

// load 4 gate rows {u+128i}, k-slice [32s,32s+32) of a [512][128] matrix.
// Land in AGPRs (unified file); pin forbids rematerialization (r2-r4 finding).
__device__ __forceinline__ void load_w(const float* __restrict__ W, int u, int s,
                                       float (&w)[4][32]) {
    #pragma unroll
    for (int i = 0; i < 4; ++i) {
        const float* wr = W + (size_t)(u + 128 * i) * HID + 32 * s;
        #pragma unroll
        for (int j = 0; j < 8; ++j) {
            float4 v = *(const float4*)(wr + 4 * j);
            w[i][4 * j + 0] = v.x; w[i][4 * j + 1] = v.y;
            w[i][4 * j + 2] = v.z; w[i][4 * j + 3] = v.w;
        }
    }
    #pragma unroll
    for (int i = 0; i < 4; ++i)
        #pragma unroll
        for (int j = 0; j < 32; ++j)
            asm volatile("" : "+v"(w[i][j]));
}

// acc[i] += dot(w[i][:], hb[0:32]) ; hb must be 16B aligned
__device__ __forceinline__ void matvec_acc(const float (&w)[4][32],
                                           const float* hb, float (&acc)[4]) {
    #pragma unroll
    for (int j = 0; j < 8; ++j) {
        float4 v = *(const float4*)(hb + 4 * j);
        float hx[4] = {v.x, v.y, v.z, v.w};
        #pragma unroll
        for (int e = 0; e < 4; ++e) {
            #pragma unroll
            for (int i = 0; i < 4; ++i)
                acc[i] = fmaf(w[i][4 * j + e], hx[e], acc[i]);
        }
    }
}

// ---------- input GEMM: out[M][512] = A[M][64] * W[512][64]^T + b1 + b2 ----------
// (unchanged, verified)

template <int K>
__global__ __launch_bounds__(256) void gemm_bt(
    const float* __restrict__ A,
    const float* __restrict__ W,
    const float* __restrict__ b1,
    const float* __restrict__ b2,
    float* __restrict__ out,
    int Nld)
{
    constexpr int LD = 68;
    __shared__ float At[K][LD];
    __shared__ float Wt[K][LD];

    const int tid = threadIdx.x;
    const int m0 = blockIdx.x * 64;
    const int n0 = blockIdx.y * 64;

    const int rot = tid & 3;
    #pragma unroll
    for (int j = 0; j < K / 16; ++j) {
        const int e = 4 * (tid + 256 * j);
        const int row = e / K;
        const int k = e % K;
        float4 va = *(const float4*)(A + (size_t)(m0 + row) * K + k);
        float4 vw = *(const float4*)(W + (size_t)(n0 + row) * K + k);
        float fa[4] = {va.x, va.y, va.z, va.w};
        float fw[4] = {vw.x, vw.y, vw.z, vw.w};
        #pragma unroll
        for (int ii = 0; ii < 4; ++ii) {
            const int i = (ii + rot) & 3;
            At[k + i][row] = fa[i];
            Wt[k + i][row] = fw[i];
        }
    }
    __syncthreads();

    const int tx = tid & 15;
    const int ty = tid >> 4;
    float acc[4][4] = {};

    #pragma unroll 4
    for (int k = 0; k < K; ++k) {
        float4 a = *(const float4*)&At[k][ty * 4];
        float4 w = *(const float4*)&Wt[k][tx * 4];
        acc[0][0] = fmaf(a.x, w.x, acc[0][0]); acc[0][1] = fmaf(a.x, w.y, acc[0][1]);
        acc[0][2] = fmaf(a.x, w.z, acc[0][2]); acc[0][3] = fmaf(a.x, w.w, acc[0][3]);
        acc[1][0] = fmaf(a.y, w.x, acc[1][0]); acc[1][1] = fmaf(a.y, w.y, acc[1][1]);
        acc[1][2] = fmaf(a.y, w.z, acc[1][2]); acc[1][3] = fmaf(a.y, w.w, acc[1][3]);
        acc[2][0] = fmaf(a.z, w.x, acc[2][0]); acc[2][1] = fmaf(a.z, w.y, acc[2][1]);
        acc[2][2] = fmaf(a.z, w.z, acc[2][2]); acc[2][3] = fmaf(a.z, w.w, acc[2][3]);
        acc[3][0] = fmaf(a.w, w.x, acc[3][0]); acc[3][1] = fmaf(a.w, w.y, acc[3][1]);
        acc[3][2] = fmaf(a.w, w.z, acc[3][2]); acc[3][3] = fmaf(a.w, w.w, acc[3][3]);
    }

    float bb[4];
    #pragma unroll
    for (int j = 0; j < 4; ++j) {
        const int n = n0 + tx * 4 + j;
        bb[j] = b1[n] + b2[n];
    }
    #pragma unroll
    for (int i = 0; i < 4; ++i) {
        const int m = m0 + ty * 4 + i;
        float4 v;
        v.x = acc[i][0] + bb[0]; v.y = acc[i][1] + bb[1];
        v.z = acc[i][2] + bb[2]; v.w = acc[i][3] + bb[3];
        *(float4*)(out + (size_t)m * Nld + n0 + tx * 4) = v;
    }
}

// ---------- fused 2-trace kernel (64 blocks x 512 threads, r8 quad structure) ----------
// r10: same per-thread layout as r8 (u=tid>>2 owns gate rows {u+128i}, s=tid&3
// k-slice [32s,32s+32)), but each block runs TWO traces sharing the same weight
// registers (w[4][32] unchanged). Doubles per-wave FMA issue per step to fill
// the ~1900-cyc dependency-stall window the r8 profile exposed, at the same
// 64-step count. Gate inputs stream from global (L2-hot), issued at the TOP of
// each step and consumed ~1000 cyc later, so nothing is outstanding when
// __syncthreads drains vmcnt (the r9 failure mode, inverted). Phase C writes
// xp1 to global scratch (one drain at phase end); phase D streams it back.
// No global ops between matvec and barrier. Math bit-identical to r8.

__global__ __launch_bounds__(512) void fused2(
    const float* __restrict__ xproj0, // [4096][512] (incl. both layer-0 biases)
    const float* __restrict__ Whh0,   // [512][128]
    const float* __restrict__ Wih1,   // [512][128]
    const float* __restrict__ bih1,   // [512]
    const float* __restrict__ bhh1,   // [512]
    const float* __restrict__ Whh1,   // [512][128]
    const float* __restrict__ Wlin,   // [128]
    const float* __restrict__ blin,   // [1]
    float* __restrict__ xp1,          // [4096][512] f32 scratch (layer-1 gate inputs)
    float* __restrict__ y)            // [4096]
{
    const int trA = 2 * blockIdx.x;   // traces trA, trA+1
    const int tid = threadIdx.x;
    const int u = tid >> 2;
    const int s = tid & 3;
    const int pu = u + 4 * (u >> 5); // padded word index for unit u

    __shared__ __align__(16) float hs[2][TLEN][140]; // [trace][t][unit], 35 KB

    float w[4][32];
    load_w(Whh0, u, s, w);

    // gate-input stream bases (element u of gate-group i at +128*i)
    const float* xA = xproj0 + (size_t)trA * TLEN * G4 + u;
    const float* xB = xA + (size_t)TLEN * G4;

    // ===== Phase B: layer-0 recurrence, 2 traces =====
    float cA = 0.0f, cB = 0.0f;
    {   // t = 0 peel: h(-1)=0, gates from xg only
        float xga[4], xgb[4];
        #pragma unroll
        for (int i = 0; i < 4; ++i) { xga[i] = xA[128 * i]; xgb[i] = xB[128 * i]; }
        if (s == 0) {
            const float za[4] = {0.f, 0.f, 0.f, 0.f};
            hs[0][0][pu] = lstm_gate(za, xga, cA);
            hs[1][0][pu] = lstm_gate(za, xgb, cB);
        }
        __syncthreads();
    }
    #pragma unroll 1
    for (int t = 1; t < TLEN; ++t) {
        // issue gate-input loads FIRST (L2-resident; consumed after the matvec)
        float xga[4], xgb[4];
        #pragma unroll
        for (int i = 0; i < 4; ++i) {
            xga[i] = xA[(size_t)t * G4 + 128 * i];
            xgb[i] = xB[(size_t)t * G4 + 128 * i];
        }
        float accA[4] = {0.f, 0.f, 0.f, 0.f};
        float accB[4] = {0.f, 0.f, 0.f, 0.f};
        matvec_acc(w, &hs[0][t - 1][36 * s], accA);
        matvec_acc(w, &hs[1][t - 1][36 * s], accB);
        #pragma unroll
        for (int i = 0; i < 4; ++i) { accA[i] = quad_reduce(accA[i]); accB[i] = quad_reduce(accB[i]); }
        if (s == 0) {
            hs[0][t][pu] = lstm_gate(accA, xga, cA);
            hs[1][t][pu] = lstm_gate(accB, xgb, cB);
        }
        __syncthreads();
    }

    // ===== Phase C: xp1 = W_ih1 @ h1 + b_ih1 + b_hh1, both traces, all t =====
    // (no per-t barriers; stores drained once at the phase-end barrier)
    load_w(Wih1, u, s, w);
    float bi[4] = {0.f, 0.f, 0.f, 0.f};
    if (s == 0) {
        #pragma unroll
        for (int i = 0; i < 4; ++i) bi[i] = bih1[u + 128 * i] + bhh1[u + 128 * i];
    }
    float* xoA = xp1 + (size_t)trA * TLEN * G4 + u;
    float* xoB = xoA + (size_t)TLEN * G4;
    #pragma unroll 1
    for (int t = 0; t < TLEN; ++t) {
        float accA[4] = {0.f, 0.f, 0.f, 0.f};
        float accB[4] = {0.f, 0.f, 0.f, 0.f};
        matvec_acc(w, &hs[0][t][36 * s], accA);
        matvec_acc(w, &hs[1][t][36 * s], accB);
        #pragma unroll
        for (int i = 0; i < 4; ++i) { accA[i] = quad_reduce(accA[i]); accB[i] = quad_reduce(accB[i]); }
        if (s == 0) {
            #pragma unroll
            for (int i = 0; i < 4; ++i) {
                xoA[(size_t)t * G4 + 128 * i] = accA[i] + bi[i];
                xoB[(size_t)t * G4 + 128 * i] = accB[i] + bi[i];
            }
        }
    }
    __syncthreads(); // drains the xp1 stores (vmcnt 0) before phase D reads them

    // ===== Phase D: layer-1 recurrence (h2 overwrites hs), 2 traces =====
    load_w(Whh1, u, s, w);
    const float* pA = xp1 + (size_t)trA * TLEN * G4 + u;
    const float* pB = pA + (size_t)TLEN * G4;
    cA = 0.0f; cB = 0.0f;
    {   // t = 0 peel
        float xga[4], xgb[4];
        #pragma unroll
        for (int i = 0; i < 4; ++i) { xga[i] = pA[128 * i]; xgb[i] = pB[128 * i]; }
        if (s == 0) {
            const float za[4] = {0.f, 0.f, 0.f, 0.f};
            hs[0][0][pu] = lstm_gate(za, xga, cA);
            hs[1][0][pu] = lstm_gate(za, xgb, cB);
        }
        __syncthreads();
    }
    #pragma unroll 1
    for (int t = 1; t < TLEN; ++t) {
        float xga[4], xgb[4];
        #pragma unroll
        for (int i = 0; i < 4; ++i) {
            xga[i] = pA[(size_t)t * G4 + 128 * i];
            xgb[i] = pB[(size_t)t * G4 + 128 * i];
        }
        float accA[4] = {0.f, 0.f, 0.f, 0.f};
        float accB[4] = {0.f, 0.f, 0.f, 0.f};
        matvec_acc(w, &hs[0][t - 1][36 * s], accA);
        matvec_acc(w, &hs[1][t - 1][36 * s], accB);
        #pragma unroll
        for (int i = 0; i < 4; ++i) { accA[i] = quad_reduce(accA[i]); accB[i] = quad_reduce(accB[i]); }
        if (s == 0) {
            hs[0][t][pu] = lstm_gate(accA, xga, cA);
            hs[1][t][pu] = lstm_gate(accB, xgb, cB);
        }
        __syncthreads();
    }

    // ===== Phase E: y = dot(h2(t), W_lin) + b_lin ; 64 (trace,t) pairs =====
    if (tid < 256) {
        const int p = tid >> 2;   // 0..63: trace-sel p>>5, timestep p&31
        const int sq = tid & 3;
        const int m = p >> 5;
        const int tq = p & 31;
        float wl[32];
        #pragma unroll
        for (int j = 0; j < 8; ++j) {
            float4 v = *(const float4*)(Wlin + 32 * sq + 4 * j);
            wl[4 * j + 0] = v.x; wl[4 * j + 1] = v.y;
            wl[4 * j + 2] = v.z; wl[4 * j + 3] = v.w;
        }
        const float* hb = &hs[m][tq][36 * sq];
        float a = 0.f;
        #pragma unroll
        for (int j = 0; j < 8; ++j) {
            float4 v = *(const float4*)(hb + 4 * j);
            a = fmaf(v.x, wl[4 * j + 0], a);
            a = fmaf(v.y, wl[4 * j + 1], a);
            a = fmaf(v.z, wl[4 * j + 2], a);
            a = fmaf(v.w, wl[4 * j + 3], a);
        }
        a = quad_reduce(a);
        if (sq == 0) y[(size_t)(trA + m) * TLEN + tq] = a + blin[0];
    }
}

// ---------- launch ----------

extern "C" void kernel_launch(void* const* d_in, const int* in_sizes, int n_in,
                              void* d_out, int out_size, void* d_ws, size_t ws_size,
                              hipStream_t stream) {
    const float* input = (const float*)d_in[0];  // [4096][64]
    const float* W_ih0 = (const float*)d_in[1];  // [512][64]
    const float* W_hh0 = (const float*)d_in[2];  // [512][128]
    const float* b_ih0 = (const float*)d_in[3];  // [512]
    const float* b_hh0 = (const float*)d_in[4];  // [512]
    const float* W_ih1 = (const float*)d_in[5];  // [512][128]
    const float* W_hh1 = (const float*)d_in[6];  // [512][128]
    const float* b_ih1 = (const float*)d_in[7];  // [512]
    const float* b_hh1 = (const float*)d_in[8];  // [512]
    const float* W_lin = (const float*)d_in[9];  // [1][128]
    const float* b_lin = (const float*)d_in[10]; // [1]
    float* out = (float*)d_out;                  // [4096]

    float* xproj0 = (float*)d_ws;                               // 8 MB
    float* xp1    = (float*)((char*)d_ws + (size_t)(8 << 20));  // 8 MB

    dim3 ggrid(BATCH / 64, G4 / 64); // (64, 8)

    // K1: xproj0 = input @ W_ih0^T + b_ih0 + b_hh0 (full-chip GEMM)
    gemm_bt<IN_DIM><<<ggrid, 256, 0, stream>>>(input, W_ih0, b_ih0, b_hh0, xproj0, G4);
    // K2: fused 2-trace LSTM0 -> xp1 -> LSTM1 -> linear readout
    fused2<<<N_TRACES / 2, 512, 0, stream>>>(xproj0, W_hh0, W_ih1, b_ih1, b_hh1,
                                             W_hh1, W_lin, b_lin, xp1, out);
}

// Round 6
// 201.449 us; speedup vs baseline: 1.6003x; 1.1399x over previous
//
#include <hip/hip_runtime.h>

#define N_TRACES 128
#define TLEN 32
#define IN_DIM 64
#define HID 128
#define G4 (4 * HID)            // 512 gate rows
#define BATCH (N_TRACES * TLEN) // 4096

// ---------- device helpers ----------

__device__ __forceinline__ float fast_sigmoid(float x) {
    return 1.0f / (1.0f + __expf(-x));
}
// tanh(x) = 1 - 2/(e^{2x}+1): stable at both extremes
__device__ __forceinline__ float fast_tanh(float x) {
    return 1.0f - 2.0f / (__expf(2.0f * x) + 1.0f);
}
// sum across the 4 lanes of a quad, result in all 4 lanes
__device__ __forceinline__ float quad_reduce(float x) {
    x += __int_as_float(__builtin_amdgcn_update_dpp(
        0, __float_as_int(x), 0xB1 /*quad_perm [1,0,3,2]*/, 0xF, 0xF, true));
    x += __int_as_float(__builtin_amdgcn_update_dpp(
        0, __float_as_int(x), 0x4E /*quad_perm [2,3,0,1]*/, 0xF, 0xF, true));
    return x;
}
// full LSTM gate update for one (trace, unit): returns h, updates c
__device__ __forceinline__ float lstm_gate(const float (&acc)[4], const float (&xg)[4],
                                           float& c) {
    const float iv = fast_sigmoid(acc[0] + xg[0]);
    const float fv = fast_sigmoid(acc[1] + xg[1]);
    const float gv = fast_tanh(acc[2] + xg[2]);
    const float ov = fast_sigmoid(acc[3] + xg[3]);
    c = fv * c + iv * gv;
    return ov * fast_tanh(c);
}

// load 8 gate rows {u0+jj+128i}, k-slice [32s,32s+32) of a [512][128] matrix.
// 256 floats/thread -> unified VGPR/AGPR file at 1 wave/SIMD (512-reg budget).
// Pin forbids rematerialization (r2-r4 finding).
__device__ __forceinline__ void load_w2(const float* __restrict__ W, int u0, int s,
                                        float (&w)[2][4][32]) {
    #pragma unroll
    for (int jj = 0; jj < 2; ++jj) {
        #pragma unroll
        for (int i = 0; i < 4; ++i) {
            const float* wr = W + (size_t)(u0 + jj + 128 * i) * HID + 32 * s;
            #pragma unroll
            for (int j = 0; j < 8; ++j) {
                float4 v = *(const float4*)(wr + 4 * j);
                w[jj][i][4 * j + 0] = v.x; w[jj][i][4 * j + 1] = v.y;
                w[jj][i][4 * j + 2] = v.z; w[jj][i][4 * j + 3] = v.w;
            }
        }
    }
    #pragma unroll
    for (int jj = 0; jj < 2; ++jj)
        #pragma unroll
        for (int i = 0; i < 4; ++i)
            #pragma unroll
            for (int j = 0; j < 32; ++j)
                asm volatile("" : "+v"(w[jj][i][j]));
}

// acc[jj][i] += dot(w[jj][i][:], hb[0:32]) ; both units share one h read.
// Per-unit FMA order identical to r8's matvec_acc -> bit-identical results.
__device__ __forceinline__ void matvec2(const float (&w)[2][4][32],
                                        const float* hb, float (&acc)[2][4]) {
    #pragma unroll
    for (int j = 0; j < 8; ++j) {
        float4 v = *(const float4*)(hb + 4 * j);
        float hx[4] = {v.x, v.y, v.z, v.w};
        #pragma unroll
        for (int e = 0; e < 4; ++e) {
            #pragma unroll
            for (int jj = 0; jj < 2; ++jj)
                #pragma unroll
                for (int i = 0; i < 4; ++i)
                    acc[jj][i] = fmaf(w[jj][i][4 * j + e], hx[e], acc[jj][i]);
        }
    }
}

// ---------- input GEMM: out[M][512] = A[M][64] * W[512][64]^T + b1 + b2 ----------
// (unchanged, verified)

template <int K>
__global__ __launch_bounds__(256) void gemm_bt(
    const float* __restrict__ A,
    const float* __restrict__ W,
    const float* __restrict__ b1,
    const float* __restrict__ b2,
    float* __restrict__ out,
    int Nld)
{
    constexpr int LD = 68;
    __shared__ float At[K][LD];
    __shared__ float Wt[K][LD];

    const int tid = threadIdx.x;
    const int m0 = blockIdx.x * 64;
    const int n0 = blockIdx.y * 64;

    const int rot = tid & 3;
    #pragma unroll
    for (int j = 0; j < K / 16; ++j) {
        const int e = 4 * (tid + 256 * j);
        const int row = e / K;
        const int k = e % K;
        float4 va = *(const float4*)(A + (size_t)(m0 + row) * K + k);
        float4 vw = *(const float4*)(W + (size_t)(n0 + row) * K + k);
        float fa[4] = {va.x, va.y, va.z, va.w};
        float fw[4] = {vw.x, vw.y, vw.z, vw.w};
        #pragma unroll
        for (int ii = 0; ii < 4; ++ii) {
            const int i = (ii + rot) & 3;
            At[k + i][row] = fa[i];
            Wt[k + i][row] = fw[i];
        }
    }
    __syncthreads();

    const int tx = tid & 15;
    const int ty = tid >> 4;
    float acc[4][4] = {};

    #pragma unroll 4
    for (int k = 0; k < K; ++k) {
        float4 a = *(const float4*)&At[k][ty * 4];
        float4 w = *(const float4*)&Wt[k][tx * 4];
        acc[0][0] = fmaf(a.x, w.x, acc[0][0]); acc[0][1] = fmaf(a.x, w.y, acc[0][1]);
        acc[0][2] = fmaf(a.x, w.z, acc[0][2]); acc[0][3] = fmaf(a.x, w.w, acc[0][3]);
        acc[1][0] = fmaf(a.y, w.x, acc[1][0]); acc[1][1] = fmaf(a.y, w.y, acc[1][1]);
        acc[1][2] = fmaf(a.y, w.z, acc[1][2]); acc[1][3] = fmaf(a.y, w.w, acc[1][3]);
        acc[2][0] = fmaf(a.z, w.x, acc[2][0]); acc[2][1] = fmaf(a.z, w.y, acc[2][1]);
        acc[2][2] = fmaf(a.z, w.z, acc[2][2]); acc[2][3] = fmaf(a.z, w.w, acc[2][3]);
        acc[3][0] = fmaf(a.w, w.x, acc[3][0]); acc[3][1] = fmaf(a.w, w.y, acc[3][1]);
        acc[3][2] = fmaf(a.w, w.z, acc[3][2]); acc[3][3] = fmaf(a.w, w.w, acc[3][3]);
    }

    float bb[4];
    #pragma unroll
    for (int j = 0; j < 4; ++j) {
        const int n = n0 + tx * 4 + j;
        bb[j] = b1[n] + b2[n];
    }
    #pragma unroll
    for (int i = 0; i < 4; ++i) {
        const int m = m0 + ty * 4 + i;
        float4 v;
        v.x = acc[i][0] + bb[0]; v.y = acc[i][1] + bb[1];
        v.z = acc[i][2] + bb[2]; v.w = acc[i][3] + bb[3];
        *(float4*)(out + (size_t)m * Nld + n0 + tx * 4) = v;
    }
}

// ---------- fused per-trace kernel (256 threads = 4 waves = 1 wave/SIMD) ----------
// r11 theory (fits r5-r10 data): step time ~= per-SIMD VALU issue (summed over
// RESIDENT waves) + fixed serial overhead. r8 had 2 barrier-lockstep waves/SIMD
// -> ~1000 cyc of issue per step; extra waves (r6) or extra in-step work (r10)
// only ADDED issue. This version puts ONE wave per SIMD: thread (up=tid>>2,
// s=tid&3) owns units {2up, 2up+1} x 4 gates, k-slice [32s,32s+32). 256 weight
// regs/thread (1-wave 512-reg budget, __launch_bounds__(256,1)); both units
// share one set of 8 ds_read_b128. Single s==0 tail, quad reduce, LDS-resident
// xp, xg prefetch, t=0 peel — all from r8. Math bit-identical to r8.

__global__ __launch_bounds__(256, 1) void fused_trace(
    const float* __restrict__ xproj0, // [4096][512] (incl. both layer-0 biases)
    const float* __restrict__ Whh0,   // [512][128]
    const float* __restrict__ Wih1,   // [512][128]
    const float* __restrict__ bih1,   // [512]
    const float* __restrict__ bhh1,   // [512]
    const float* __restrict__ Whh1,   // [512][128]
    const float* __restrict__ Wlin,   // [128]
    const float* __restrict__ blin,   // [1]
    float* __restrict__ y)            // [4096]
{
    const int trace = blockIdx.x;
    const int tid = threadIdx.x;
    const int up = tid >> 2;            // unit pair 0..63
    const int s = tid & 3;              // k-slice 0..3
    const int u0 = 2 * up;              // first owned unit
    const int pu = u0 + 4 * (u0 >> 5);  // padded word for u0 (u0+1 -> pu+1, same 32-block)

    __shared__ float hs[TLEN][140];     // h1 then h2, padded (p(127)=139)
    __shared__ float xp[TLEN * G4];     // 64 KB: xproj0, then overwritten w/ xproj1

    float w[2][4][32];

    // ===== Preload xproj0 -> LDS (coalesced float4) =====
    const float* xpb = xproj0 + (size_t)trace * TLEN * G4;
    #pragma unroll
    for (int j = 0; j < 16; ++j) {
        const int f4 = j * 256 + tid;
        float4 v = *(const float4*)(xpb + 4 * f4);
        *(float4*)(&xp[4 * f4]) = v;
    }
    load_w2(Whh0, u0, s, w);
    __syncthreads();

    // ===== Phase B: layer-0 recurrence =====
    float xg[2][4], xgn[2][4];
    #pragma unroll
    for (int jj = 0; jj < 2; ++jj)
        #pragma unroll
        for (int i = 0; i < 4; ++i) xg[jj][i] = xp[128 * i + u0 + jj];      // t=0
    #pragma unroll
    for (int jj = 0; jj < 2; ++jj)
        #pragma unroll
        for (int i = 0; i < 4; ++i) xgn[jj][i] = xp[G4 + 128 * i + u0 + jj]; // t=1

    float c0 = 0.0f, c1 = 0.0f;
    // t=0 peel: no recurrent matvec (h(-1)=0)
    if (s == 0) {
        const float za[4] = {0.f, 0.f, 0.f, 0.f};
        hs[0][pu]     = lstm_gate(za, xg[0], c0);
        hs[0][pu + 1] = lstm_gate(za, xg[1], c1);
    }
    __syncthreads();

    #pragma unroll 1
    for (int t = 1; t < TLEN; ++t) {
        #pragma unroll
        for (int jj = 0; jj < 2; ++jj)
            #pragma unroll
            for (int i = 0; i < 4; ++i) xg[jj][i] = xgn[jj][i];

        float acc[2][4] = {};
        matvec2(w, &hs[t - 1][36 * s], acc);
        #pragma unroll
        for (int jj = 0; jj < 2; ++jj)
            #pragma unroll
            for (int i = 0; i < 4; ++i) acc[jj][i] = quad_reduce(acc[jj][i]);

        if (s == 0) {
            hs[t][pu]     = lstm_gate(acc[0], xg[0], c0);
            hs[t][pu + 1] = lstm_gate(acc[1], xg[1], c1);
        }
        // prefetch next step's gate inputs (xp read-only in this phase)
        if (t < TLEN - 1) {
            #pragma unroll
            for (int jj = 0; jj < 2; ++jj)
                #pragma unroll
                for (int i = 0; i < 4; ++i)
                    xgn[jj][i] = xp[(t + 1) * G4 + 128 * i + u0 + jj];
        }
        __syncthreads();
    }

    // ===== Phase C: xp[t] = W_ih1 @ h1(t) + b_ih1 + b_hh1 (no per-t barrier) =====
    load_w2(Wih1, u0, s, w);
    float bi[2][4] = {};
    if (s == 0) {
        #pragma unroll
        for (int jj = 0; jj < 2; ++jj)
            #pragma unroll
            for (int i = 0; i < 4; ++i)
                bi[jj][i] = bih1[u0 + jj + 128 * i] + bhh1[u0 + jj + 128 * i];
    }
    #pragma unroll 1
    for (int t = 0; t < TLEN; ++t) {
        float acc[2][4] = {};
        matvec2(w, &hs[t][36 * s], acc);
        #pragma unroll
        for (int jj = 0; jj < 2; ++jj)
            #pragma unroll
            for (int i = 0; i < 4; ++i) acc[jj][i] = quad_reduce(acc[jj][i]);
        if (s == 0) {
            #pragma unroll
            for (int jj = 0; jj < 2; ++jj)
                #pragma unroll
                for (int i = 0; i < 4; ++i)
                    xp[t * G4 + 128 * i + u0 + jj] = acc[jj][i] + bi[jj][i];
        }
    }
    __syncthreads();

    // ===== Phase D: layer-1 recurrence (h2 overwrites hs) =====
    load_w2(Whh1, u0, s, w);
    #pragma unroll
    for (int jj = 0; jj < 2; ++jj)
        #pragma unroll
        for (int i = 0; i < 4; ++i) xg[jj][i] = xp[128 * i + u0 + jj];      // t=0
    #pragma unroll
    for (int jj = 0; jj < 2; ++jj)
        #pragma unroll
        for (int i = 0; i < 4; ++i) xgn[jj][i] = xp[G4 + 128 * i + u0 + jj]; // t=1

    c0 = 0.0f; c1 = 0.0f;
    // t=0 peel
    if (s == 0) {
        const float za[4] = {0.f, 0.f, 0.f, 0.f};
        hs[0][pu]     = lstm_gate(za, xg[0], c0);
        hs[0][pu + 1] = lstm_gate(za, xg[1], c1);
    }
    __syncthreads();

    #pragma unroll 1
    for (int t = 1; t < TLEN; ++t) {
        #pragma unroll
        for (int jj = 0; jj < 2; ++jj)
            #pragma unroll
            for (int i = 0; i < 4; ++i) xg[jj][i] = xgn[jj][i];

        float acc[2][4] = {};
        matvec2(w, &hs[t - 1][36 * s], acc);
        #pragma unroll
        for (int jj = 0; jj < 2; ++jj)
            #pragma unroll
            for (int i = 0; i < 4; ++i) acc[jj][i] = quad_reduce(acc[jj][i]);

        if (s == 0) {
            hs[t][pu]     = lstm_gate(acc[0], xg[0], c0);
            hs[t][pu + 1] = lstm_gate(acc[1], xg[1], c1);
        }
        if (t < TLEN - 1) {
            #pragma unroll
            for (int jj = 0; jj < 2; ++jj)
                #pragma unroll
                for (int i = 0; i < 4; ++i)
                    xgn[jj][i] = xp[(t + 1) * G4 + 128 * i + u0 + jj];
        }
        __syncthreads();
    }

    // ===== Phase E: y[trace*32+t] = dot(h2(t), W_lin) + b_lin =====
    if (tid < 128) {
        const int tq = tid >> 2;
        const int sq = tid & 3;
        float wl[32];
        #pragma unroll
        for (int j = 0; j < 8; ++j) {
            float4 v = *(const float4*)(Wlin + 32 * sq + 4 * j);
            wl[4 * j + 0] = v.x; wl[4 * j + 1] = v.y;
            wl[4 * j + 2] = v.z; wl[4 * j + 3] = v.w;
        }
        const float* hb = &hs[tq][36 * sq];
        float a = 0.f;
        #pragma unroll
        for (int j = 0; j < 8; ++j) {
            float4 v = *(const float4*)(hb + 4 * j);
            a = fmaf(v.x, wl[4 * j + 0], a);
            a = fmaf(v.y, wl[4 * j + 1], a);
            a = fmaf(v.z, wl[4 * j + 2], a);
            a = fmaf(v.w, wl[4 * j + 3], a);
        }
        a = quad_reduce(a);
        if (sq == 0) y[trace * TLEN + tq] = a + blin[0];
    }
}

// ---------- launch ----------

extern "C" void kernel_launch(void* const* d_in, const int* in_sizes, int n_in,
                              void* d_out, int out_size, void* d_ws, size_t ws_size,
                              hipStream_t stream) {
    const float* input = (const float*)d_in[0];  // [4096][64]
    const float* W_ih0 = (const float*)d_in[1];  // [512][64]
    const float* W_hh0 = (const float*)d_in[2];  // [512][128]
    const float* b_ih0 = (const float*)d_in[3];  // [512]
    const float* b_hh0 = (const float*)d_in[4];  // [512]
    const float* W_ih1 = (const float*)d_in[5];  // [512][128]
    const float* W_hh1 = (const float*)d_in[6];  // [512][128]
    const float* b_ih1 = (const float*)d_in[7];  // [512]
    const float* b_hh1 = (const float*)d_in[8];  // [512]
    const float* W_lin = (const float*)d_in[9];  // [1][128]
    const float* b_lin = (const float*)d_in[10]; // [1]
    float* out = (float*)d_out;                  // [4096]

    float* xproj0 = (float*)d_ws; // [4096][512], 8 MB

    dim3 ggrid(BATCH / 64, G4 / 64); // (64, 8)

    // K1: xproj0 = input @ W_ih0^T + b_ih0 + b_hh0 (full-chip GEMM)
    gemm_bt<IN_DIM><<<ggrid, 256, 0, stream>>>(input, W_ih0, b_ih0, b_hh0, xproj0, G4);
    // K2: fused per-trace LSTM0 -> xproj1 -> LSTM1 -> linear readout
    fused_trace<<<N_TRACES, 256, 0, stream>>>(xproj0, W_hh0, W_ih1, b_ih1, b_hh1,
                                              W_hh1, W_lin, b_lin, out);
}